// Round 14
// baseline (313.853 us; speedup 1.0000x reference)
//
#include <hip/hip_runtime.h>
#include <hip/hip_bf16.h>
#include <math.h>

#define BB   64
#define NN   784
#define DD   768
#define HH   32
#define HD24 24
#define MM   785
#define HIDN 3072
#define QSCALE 0.20412414523193154f
#define LNEPS 1e-6f

// ---- workspace layout (float offsets) ----
#define WS_Q     0          // [64][768]
#define WS_RS    49152      // [64][800]
#define WS_RM    100352     // [64][800]
#define WS_S1P   151552     // [64][6][32]
#define WS_BQP   163840     // [64][6][32]
#define WS_LMX   176128     // [64][4][32]
#define WS_LSM   184320
#define WS_A2P   192512
#define WS_WMP   200704
#define WS_PS    208896     // [64][12][2]
#define WS_C1    210432     // [64][768]
#define WS_H2    259584     // [64][3072]
#define WS_O     456192     // [64][768]
#define WS_E     505344     // GQB bf16-frag (d2-d3), then E/W [64][32][800] (d4-d6)
#define WS_T     2143744    // t [64][785][32] (d3-d4), then r [64][32][768] (d6-d7)
#define WS_T2    3751424    // t-half-2 (d3-d4) [ksplit only]
#define WS_SLQ   5359104    // [64][2][800][2] partial LN stats (ksplit only)
#define WS_KSEND 5563904    // gate: ksplit needs ws_size >= this * 4 bytes
#define WS_ZP    0          // [4][64][768] overlay (d10-d11)

typedef __attribute__((ext_vector_type(8))) short bf16x8;
typedef __attribute__((ext_vector_type(4))) float f32x4;

__device__ __forceinline__ unsigned packbf(float a, float b) {
  union { __hip_bfloat162 h2; unsigned u; } cv;
  cv.h2 = __float22bfloat162_rn(make_float2(a, b));
  return cv.u;
}

// ============================================================
// d1: q = (LN(x_cls) @ Wq + bq) * QSCALE     grid (12, 64)
// ============================================================
__global__ __launch_bounds__(256) void k_q(
    const float* __restrict__ x_cls,
    const float* __restrict__ g1, const float* __restrict__ b1,
    const float* __restrict__ Wq, const float* __restrict__ bq,
    float* __restrict__ ws)
{
  const int b = blockIdx.y;
  const int oc0 = blockIdx.x * 64;
  const int t = threadIdx.x;
  const int lane = t & 63, wid = t >> 6;

  __shared__ __align__(16) float nc_l[DD];
  __shared__ float red4[4][64];
  __shared__ float rS[4], rQ[4];
  __shared__ float musd[2];

  float xv[3];
  float s = 0.f, q2 = 0.f;
#pragma unroll
  for (int k = 0; k < 3; ++k) {
    float v = x_cls[(size_t)b * DD + t + 256 * k];
    xv[k] = v; s += v; q2 += v * v;
  }
#pragma unroll
  for (int off = 1; off < 64; off <<= 1) { s += __shfl_xor(s, off); q2 += __shfl_xor(q2, off); }
  if (lane == 0) { rS[wid] = s; rQ[wid] = q2; }
  __syncthreads();
  if (t == 0) {
    float ss = rS[0] + rS[1] + rS[2] + rS[3];
    float qq = rQ[0] + rQ[1] + rQ[2] + rQ[3];
    float mu = ss * (1.f / DD);
    musd[0] = mu; musd[1] = rsqrtf(qq * (1.f / DD) - mu * mu + LNEPS);
  }
  __syncthreads();
  {
    float mu = musd[0], rs = musd[1];
#pragma unroll
    for (int k = 0; k < 3; ++k) {
      int d = t + 256 * k;
      nc_l[d] = (xv[k] - mu) * rs * g1[d] + b1[d];
    }
  }
  __syncthreads();

  const int oc = t & 63, ks = t >> 6;
  const float* wp = Wq + (size_t)(ks * 192) * DD + oc0 + oc;
  const float* ncp = nc_l + ks * 192;
  float a0 = 0.f, a1 = 0.f, a2 = 0.f, a3 = 0.f;
#pragma unroll 4
  for (int d = 0; d < 192; d += 4) {
    a0 += ncp[d + 0] * wp[(size_t)(d + 0) * DD];
    a1 += ncp[d + 1] * wp[(size_t)(d + 1) * DD];
    a2 += ncp[d + 2] * wp[(size_t)(d + 2) * DD];
    a3 += ncp[d + 3] * wp[(size_t)(d + 3) * DD];
  }
  red4[ks][oc] = (a0 + a1) + (a2 + a3);
  __syncthreads();
  if (t < 64) {
    int ocg = oc0 + t;
    ws[WS_Q + (size_t)b * DD + ocg] =
        (red4[0][t] + red4[1][t] + red4[2][t] + red4[3][t] + bq[ocg]) * QSCALE;
  }
}

// ============================================================
// d2: gq = fold(T1, qk) ; write bf16 MFMA-B-fragment-swizzled GQB;
// partial s1, bqs.  grid (6 d-tiles of 128, 64)
// ============================================================
__global__ __launch_bounds__(256) void k_gqk(
    const float* __restrict__ g1, const float* __restrict__ b1,
    const float* __restrict__ Wk, const float* __restrict__ w1W,
    float* __restrict__ ws)
{
  const int b = blockIdx.y;
  const int d0 = blockIdx.x * 128;
  const int t = threadIdx.x;

  __shared__ __align__(16) float q_l[DD];
  __shared__ float T1[HH * HH];
  __shared__ float qk_l[128][33];
  __shared__ float pS[8][HH], pB[8][HH];

  for (int i = t; i < DD; i += 256) q_l[i] = ws[WS_Q + (size_t)b * DD + i];
  for (int i = t; i < HH * HH; i += 256) {
    int g = i >> 5, h = i & 31;
    T1[i] = w1W[i] + ((g == h) ? 1.f : 0.f);
  }
  __syncthreads();

  { // phase 1: qk[d][g]
    const int dl = t >> 1, gh = t & 1;
    const float4* wr = (const float4*)(Wk + (size_t)(d0 + dl) * DD + gh * 384);
    const float4* qr = (const float4*)(q_l + gh * 384);
#pragma unroll 4
    for (int gg = 0; gg < 16; ++gg) {
      float a = 0.f;
#pragma unroll
      for (int c = 0; c < 6; ++c) {
        float4 w = wr[gg * 6 + c];
        float4 p = qr[gg * 6 + c];
        a += w.x * p.x + w.y * p.y + w.z * p.z + w.w * p.w;
      }
      qk_l[dl][gh * 16 + gg] = a;
    }
  }
  __syncthreads();
  { // phase 2: mix + write bf16 swizzled GQB + partials
    const int h = t & 31, dg = t >> 5;
    float fb[16];
    float s1a = 0.f, bqa = 0.f;
#pragma unroll 2
    for (int dd = 0; dd < 16; ++dd) {
      int dl = dg * 16 + dd;
      float f = 0.f;
#pragma unroll 8
      for (int g = 0; g < HH; ++g) f += qk_l[dl][g] * T1[g * HH + h];
      float gq = g1[d0 + dl] * f;
      fb[dd] = gq;
      s1a += gq;
      bqa += b1[d0 + dl] * qk_l[dl][h];
    }
    const int kstep = (d0 >> 5) + (dg >> 1);
    const int nt = h >> 4;
    const int lane0 = (h & 15) + 32 * (dg & 1);
    uint4* GQB = (uint4*)(ws + WS_E) + (size_t)b * (24 * 2 * 64);
    GQB[(kstep * 2 + nt) * 64 + lane0] =
        make_uint4(packbf(fb[0], fb[1]), packbf(fb[2], fb[3]),
                   packbf(fb[4], fb[5]), packbf(fb[6], fb[7]));
    GQB[(kstep * 2 + nt) * 64 + lane0 + 16] =
        make_uint4(packbf(fb[8], fb[9]), packbf(fb[10], fb[11]),
                   packbf(fb[12], fb[13]), packbf(fb[14], fb[15]));
    pS[dg][h] = s1a; pB[dg][h] = bqa;
  }
  __syncthreads();
  if (t < HH) {
    float s = 0.f, bq = 0.f;
#pragma unroll
    for (int k = 0; k < 8; ++k) { s += pS[k][t]; bq += pB[k][t]; }
    ws[WS_S1P + ((size_t)b * 6 + blockIdx.x) * HH + t] = s;
    ws[WS_BQP + ((size_t)b * 6 + blockIdx.x) * HH + t] = bq;
  }
}

// ============================================================
// d3: big pass 1 (MFMA, lean). 64 rows/block, grid (13, 64, nz), 4 waves.
// ============================================================
__global__ __launch_bounds__(256) void k_main1(
    const float* __restrict__ x_cls, const float* __restrict__ x_img,
    float* __restrict__ ws)
{
  const int b = blockIdx.y;
  const int m0 = blockIdx.x * 64;
  const int nz = gridDim.z;
  const int kh = blockIdx.z;
  const int t = threadIdx.x;
  const int w = t >> 6;
  const int l = t & 63;
  const int lg = l >> 4;       // k-octet within 32-step
  const int lm = l & 15;       // A-row / B-col within 16-tile

  const uint4* GQ = (const uint4*)(ws + WS_E) + (size_t)b * (24 * 2 * 64);

  const int arow = m0 + w * 16 + lm;
  const bool av = (arow < MM);
  const int arc = av ? arow : 0;
  const float* asrc = (arc == 0) ? (x_cls + (size_t)b * DD)
                                 : (x_img + ((size_t)b * NN + (arc - 1)) * DD);
  const int nk = 24 / nz;
  const int k0 = kh * nk;

  f32x4 acc0 = {0.f, 0.f, 0.f, 0.f};
  f32x4 acc1 = {0.f, 0.f, 0.f, 0.f};
  float sl = 0.f, sq = 0.f;

#pragma unroll 4
  for (int kst = k0; kst < k0 + nk; ++kst) {
    float4 a0 = make_float4(0.f, 0.f, 0.f, 0.f);
    float4 a1 = make_float4(0.f, 0.f, 0.f, 0.f);
    if (av) {
      a0 = *(const float4*)(asrc + kst * 32 + 8 * lg);
      a1 = *(const float4*)(asrc + kst * 32 + 8 * lg + 4);
    }
    sl += (a0.x + a0.y) + (a0.z + a0.w) + (a1.x + a1.y) + (a1.z + a1.w);
    sq += a0.x*a0.x + a0.y*a0.y + a0.z*a0.z + a0.w*a0.w
        + a1.x*a1.x + a1.y*a1.y + a1.z*a1.z + a1.w*a1.w;
    union { uint4 u; bf16x8 h; } ua, ub0, ub1;
    ua.u = make_uint4(packbf(a0.x, a0.y), packbf(a0.z, a0.w),
                      packbf(a1.x, a1.y), packbf(a1.z, a1.w));
    ub0.u = GQ[(kst * 2 + 0) * 64 + l];
    ub1.u = GQ[(kst * 2 + 1) * 64 + l];
    acc0 = __builtin_amdgcn_mfma_f32_16x16x32_bf16(ua.h, ub0.h, acc0, 0, 0, 0);
    acc1 = __builtin_amdgcn_mfma_f32_16x16x32_bf16(ua.h, ub1.h, acc1, 0, 0, 0);
  }

  sl += __shfl_xor(sl, 16); sl += __shfl_xor(sl, 32);
  sq += __shfl_xor(sq, 16); sq += __shfl_xor(sq, 32);
  if (lg == 0 && av) {
    if (nz == 1) {
      float mu = sl * (1.f / DD);
      float rs = rsqrtf(sq * (1.f / DD) - mu * mu + LNEPS);
      ws[WS_RS + (size_t)b * 800 + arow] = rs;
      ws[WS_RM + (size_t)b * 800 + arow] = rs * mu;
    } else {
      float* slq = ws + WS_SLQ + (((size_t)b * 2 + kh) * 800 + arow) * 2;
      slq[0] = sl; slq[1] = sq;
    }
  }

  float* tb = ws + (kh ? WS_T2 : WS_T) + (size_t)b * MM * HH;
#pragma unroll
  for (int r = 0; r < 4; ++r) {
    int row = m0 + w * 16 + 4 * lg + r;
    if (row < MM) {
      tb[(size_t)row * HH + lm] = acc0[r];
      tb[(size_t)row * HH + 16 + lm] = acc1[r];
    }
  }
}

// ============================================================
// d4: online softmax pass A. grid (4 m-chunks, 64).
// ============================================================
__global__ __launch_bounds__(256) void k_sm_a(
    const float* __restrict__ bk,
    const float* __restrict__ w1W, const float* __restrict__ w1b,
    float* __restrict__ ws, int ksplit)
{
  const int cx = blockIdx.x, b = blockIdx.y;
  const int t = threadIdx.x;
  const int lane = t & 63, wid = t >> 6;

  __shared__ float T1[HH * HH];
  __shared__ float s1_sh[HH], c0_sh[HH], bq_sh[HH];
  __shared__ float red[4][HH];
  __shared__ float lmax_sh[HH];

  for (int i = t; i < HH * HH; i += 256) {
    int g = i >> 5, h = i & 31;
    T1[i] = w1W[i] + ((g == h) ? 1.f : 0.f);
  }
  if (t < HH) {
    float s1v = 0.f, bqv = 0.f;
#pragma unroll
    for (int p = 0; p < 6; ++p) {
      s1v += ws[WS_S1P + ((size_t)b * 6 + p) * HH + t];
      bqv += ws[WS_BQP + ((size_t)b * 6 + p) * HH + t];
    }
    const float* qp = ws + WS_Q + (size_t)b * DD + t * HD24;
#pragma unroll
    for (int j = 0; j < HD24; ++j) bqv += bk[t * HD24 + j] * qp[j];
    s1_sh[t] = s1v; bq_sh[t] = bqv;
  }
  __syncthreads();
  if (t < HH) {
    float c0 = w1b[t];
#pragma unroll
    for (int g = 0; g < HH; ++g) c0 += T1[g * HH + t] * bq_sh[g];
    c0_sh[t] = c0;
  }
  __syncthreads();

  const int m = cx * 256 + t;
  const bool vm = (m < MM);
  float a1[HH];
  if (vm) {
    const float* tb = ws + WS_T + ((size_t)b * MM + m) * HH;
    const float* tb2 = ws + WS_T2 + ((size_t)b * MM + m) * HH;
    float rs, rm;
    if (ksplit) {
      const float* slq = ws + WS_SLQ + ((size_t)b * 2 * 800 + m) * 2;
      float sl = slq[0] + slq[(size_t)800 * 2];
      float sq = slq[1] + slq[(size_t)800 * 2 + 1];
      float mu = sl * (1.f / DD);
      rs = rsqrtf(sq * (1.f / DD) - mu * mu + LNEPS);
      rm = rs * mu;
      ws[WS_RS + (size_t)b * 800 + m] = rs;
      ws[WS_RM + (size_t)b * 800 + m] = rm;
    } else {
      rs = ws[WS_RS + (size_t)b * 800 + m];
      rm = ws[WS_RM + (size_t)b * 800 + m];
    }
#pragma unroll
    for (int q = 0; q < 8; ++q) {
      float4 tv = *(const float4*)(tb + q * 4);
      if (ksplit) {
        float4 t2 = *(const float4*)(tb2 + q * 4);
        tv.x += t2.x; tv.y += t2.y; tv.z += t2.z; tv.w += t2.w;
      }
      a1[4*q+0] = rs * tv.x - rm * s1_sh[4*q+0] + c0_sh[4*q+0];
      a1[4*q+1] = rs * tv.y - rm * s1_sh[4*q+1] + c0_sh[4*q+1];
      a1[4*q+2] = rs * tv.z - rm * s1_sh[4*q+2] + c0_sh[4*q+2];
      a1[4*q+3] = rs * tv.w - rm * s1_sh[4*q+3] + c0_sh[4*q+3];
    }
  } else {
#pragma unroll
    for (int h = 0; h < HH; ++h) a1[h] = -3.0e38f;
  }
#pragma unroll
  for (int h = 0; h < HH; ++h) {
    float v = a1[h];
#pragma unroll
    for (int off = 1; off < 64; off <<= 1) v = fmaxf(v, __shfl_xor(v, off));
    if (lane == 0) red[wid][h] = v;
  }
  __syncthreads();
  if (t < HH) {
    float v = fmaxf(fmaxf(red[0][t], red[1][t]), fmaxf(red[2][t], red[3][t]));
    lmax_sh[t] = v;
    ws[WS_LMX + ((size_t)b * 4 + cx) * HH + t] = v;
  }
  __syncthreads();
  float* E = ws + WS_E + (size_t)b * (HH * 800);
  if (vm) {
#pragma unroll
    for (int h = 0; h < HH; ++h) {
      float e = __expf(a1[h] - lmax_sh[h]);
      a1[h] = e;
      E[(size_t)h * 800 + m] = e;
    }
  } else {
#pragma unroll
    for (int h = 0; h < HH; ++h) a1[h] = 0.f;
  }
#pragma unroll
  for (int h = 0; h < HH; ++h) {
    float v = a1[h];
#pragma unroll
    for (int off = 1; off < 64; off <<= 1) v += __shfl_xor(v, off);
    if (lane == 0) red[wid][h] = v;
  }
  __syncthreads();
  if (t < HH)
    ws[WS_LSM + ((size_t)b * 4 + cx) * HH + t] = red[0][t] + red[1][t] + red[2][t] + red[3][t];
}

// ============================================================
// d5: softmax pass B. grid (4, 64).
// ============================================================
__global__ __launch_bounds__(256) void k_sm_b(
    const float* __restrict__ w2W, const float* __restrict__ w2b,
    float* __restrict__ ws)
{
  const int cx = blockIdx.x, b = blockIdx.y;
  const int t = threadIdx.x;
  const int lane = t & 63, wid = t >> 6;

  __shared__ __align__(16) float T2s[HH * HH];
  __shared__ float inv_sh[HH], w2b_sh[HH];
  __shared__ float red[4][HH];

  if (t < HH) {
    float l0 = ws[WS_LMX + ((size_t)b * 4 + 0) * HH + t];
    float l1 = ws[WS_LMX + ((size_t)b * 4 + 1) * HH + t];
    float l2 = ws[WS_LMX + ((size_t)b * 4 + 2) * HH + t];
    float l3 = ws[WS_LMX + ((size_t)b * 4 + 3) * HH + t];
    float gmax = fmaxf(fmaxf(l0, l1), fmaxf(l2, l3));
    float s = ws[WS_LSM + ((size_t)b * 4 + 0) * HH + t] * __expf(l0 - gmax)
            + ws[WS_LSM + ((size_t)b * 4 + 1) * HH + t] * __expf(l1 - gmax)
            + ws[WS_LSM + ((size_t)b * 4 + 2) * HH + t] * __expf(l2 - gmax)
            + ws[WS_LSM + ((size_t)b * 4 + 3) * HH + t] * __expf(l3 - gmax);
    float lcx = (cx == 0) ? l0 : (cx == 1) ? l1 : (cx == 2) ? l2 : l3;
    inv_sh[t] = __expf(lcx - gmax) / s;
    w2b_sh[t] = w2b[t];
  }
  __syncthreads();
  for (int i = t; i < HH * HH; i += 256) {
    int g = i >> 5, h = i & 31;
    T2s[i] = (w2W[i] + ((g == h) ? 1.f : 0.f)) * inv_sh[g];
  }
  __syncthreads();

  const int m = cx * 256 + t;
  float* E = ws + WS_E + (size_t)b * (HH * 800);
  float4 av[8];
#pragma unroll
  for (int q = 0; q < 8; ++q) av[q] = make_float4(0.f,0.f,0.f,0.f);
  float rm = 0.f;
  if (m < MM) {
    float rs = ws[WS_RS + (size_t)b * 800 + m];
    rm = ws[WS_RM + (size_t)b * 800 + m];
#pragma unroll 4
    for (int g = 0; g < HH; ++g) {
      float eg = E[(size_t)g * 800 + m];
#pragma unroll
      for (int q = 0; q < 8; ++q) {
        float4 t2 = *(const float4*)&T2s[g * HH + q * 4];
        av[q].x += eg * t2.x; av[q].y += eg * t2.y;
        av[q].z += eg * t2.z; av[q].w += eg * t2.w;
      }
    }
#pragma unroll
    for (int q = 0; q < 8; ++q) {
      av[q].x += w2b_sh[q*4+0]; av[q].y += w2b_sh[q*4+1];
      av[q].z += w2b_sh[q*4+2]; av[q].w += w2b_sh[q*4+3];
      E[(size_t)(q*4+0) * 800 + m] = av[q].x * rs;
      E[(size_t)(q*4+1) * 800 + m] = av[q].y * rs;
      E[(size_t)(q*4+2) * 800 + m] = av[q].z * rs;
      E[(size_t)(q*4+3) * 800 + m] = av[q].w * rs;
    }
  } else if (m < 800) {
#pragma unroll
    for (int h = 0; h < HH; ++h) E[(size_t)h * 800 + m] = 0.f;
  }
#pragma unroll
  for (int h = 0; h < HH; ++h) {
    float v = ((const float*)&av[h >> 2])[h & 3];
#pragma unroll
    for (int off = 1; off < 64; off <<= 1) v += __shfl_xor(v, off);
    if (lane == 0) red[wid][h] = v;
  }
  __syncthreads();
  if (t < HH)
    ws[WS_A2P + ((size_t)b * 4 + cx) * HH + t] = red[0][t] + red[1][t] + red[2][t] + red[3][t];
  __syncthreads();
#pragma unroll
  for (int h = 0; h < HH; ++h) {
    float v = ((const float*)&av[h >> 2])[h & 3] * rm;
#pragma unroll
    for (int off = 1; off < 64; off <<= 1) v += __shfl_xor(v, off);
    if (lane == 0) red[wid][h] = v;
  }
  __syncthreads();
  if (t < HH)
    ws[WS_WMP + ((size_t)b * 4 + cx) * HH + t] = red[0][t] + red[1][t] + red[2][t] + red[3][t];
}

// ============================================================
// d6: r[b][h][d] = sum_m w[h][m] * u[m][d]  + fused x_img->out copy.
// 512 thr, 8 waves (m-halves in-block), LDS r-combine. grid (12, 64).
// NO LDS staging for W: wave-uniform f4 reads straight from global
// (L2-hot, L1 broadcast) -> ZERO barriers in the main loop.
// ============================================================
__global__ __launch_bounds__(512) void k_wsum(
    const float* __restrict__ x_cls, const float* __restrict__ x_img,
    float* __restrict__ out, float* __restrict__ ws)
{
  const int b = blockIdx.y;
  const int d0 = blockIdx.x * 64;
  const int t = threadIdx.x;
  const int wv = t >> 6;
  const int mh = wv >> 2;          // m-half (0/1)
  const int hw = wv & 3;           // head-quarter AND copy-row-owner
  const int hb = hw * 8;
  const int dseg = t & 15;
  const int msub = (t >> 4) & 3;
  const int mcBeg = mh * 13;
  const int mcN = 13 - mh;         // 13 or 12 chunks

  __shared__ __align__(16) float r_s[HH][68];

  const float* W = ws + WS_E + (size_t)b * (HH * 800);
  float* out_img = out + (size_t)BB * DD;

  float acc[8][4];
#pragma unroll
  for (int j = 0; j < 8; ++j)
#pragma unroll
    for (int c = 0; c < 4; ++c) acc[j][c] = 0.f;

  float4 pu[8], pun[8];

  auto LOADU = [&](int j, float4* dst) {
#pragma unroll
    for (int i = 0; i < 8; ++i) {
      int m = (mcBeg + j) * 32 + msub * 8 + i;
      if (j < mcN && m < MM) {
        const float* src = (m == 0) ? (x_cls + (size_t)b * DD)
                                    : (x_img + ((size_t)b * NN + (m - 1)) * DD);
        dst[i] = *(const float4*)(src + d0 + dseg * 4);
      } else dst[i] = make_float4(0.f,0.f,0.f,0.f);
    }
  };

  LOADU(0, pu);
  for (int j = 0; j < mcN; ++j) {
    if (j + 1 < mcN) LOADU(j + 1, pun);
    const int mbase = (mcBeg + j) * 32 + msub * 8;
#pragma unroll
    for (int jj = 0; jj < 8; ++jj) {
      const float* Wr = W + (size_t)(hb + jj) * 800 + mbase;
      float4 wA = *(const float4*)(Wr);
      float4 wB = *(const float4*)(Wr + 4);
      float wv0 = wA.x, wv1 = wA.y, wv2 = wA.z, wv3 = wA.w;
      float wv4 = wB.x, wv5 = wB.y, wv6 = wB.z, wv7 = wB.w;
      acc[jj][0] += wv0*pu[0].x + wv1*pu[1].x + wv2*pu[2].x + wv3*pu[3].x
                  + wv4*pu[4].x + wv5*pu[5].x + wv6*pu[6].x + wv7*pu[7].x;
      acc[jj][1] += wv0*pu[0].y + wv1*pu[1].y + wv2*pu[2].y + wv3*pu[3].y
                  + wv4*pu[4].y + wv5*pu[5].y + wv6*pu[6].y + wv7*pu[7].y;
      acc[jj][2] += wv0*pu[0].z + wv1*pu[1].z + wv2*pu[2].z + wv3*pu[3].z
                  + wv4*pu[4].z + wv5*pu[5].z + wv6*pu[6].z + wv7*pu[7].z;
      acc[jj][3] += wv0*pu[0].w + wv1*pu[1].w + wv2*pu[2].w + wv3*pu[3].w
                  + wv4*pu[4].w + wv5*pu[5].w + wv6*pu[6].w + wv7*pu[7].w;
    }
    // fused copy-out of chunk j: wave-quarter hw stores subrows {2hw, 2hw+1}
#pragma unroll
    for (int i = 0; i < 8; ++i) {
      if ((i >> 1) == hw) {
        int m = (mcBeg + j) * 32 + msub * 8 + i;
        if (m >= 1 && m < MM)
          *(float4*)(out_img + ((size_t)b * NN + (m - 1)) * DD + d0 + dseg * 4) = pu[i];
      }
    }
    if (j + 1 < mcN) {
#pragma unroll
      for (int i = 0; i < 8; ++i) pu[i] = pun[i];
    }
  }

  // reduce over msub (lanes 16, 32 apart)
#pragma unroll
  for (int j = 0; j < 8; ++j)
#pragma unroll
    for (int c = 0; c < 4; ++c) {
      float v = acc[j][c];
      v += __shfl_xor(v, 16);
      v += __shfl_xor(v, 32);
      acc[j][c] = v;
    }
  // cross-half combine via LDS
  __syncthreads();
  if (mh == 1 && msub == 0) {
#pragma unroll
    for (int j = 0; j < 8; ++j)
      *(float4*)&r_s[hb + j][dseg * 4] =
          make_float4(acc[j][0], acc[j][1], acc[j][2], acc[j][3]);
  }
  __syncthreads();
  if (mh == 0 && msub == 0) {
    float* R = ws + WS_T + (size_t)b * HH * DD;
#pragma unroll
    for (int j = 0; j < 8; ++j) {
      float4 rv = *(const float4*)&r_s[hb + j][dseg * 4];
      *(float4*)(R + (size_t)(hb + j) * DD + d0 + dseg * 4) =
          make_float4(acc[j][0] + rv.x, acc[j][1] + rv.y,
                      acc[j][2] + rv.z, acc[j][3] + rv.w);
    }
  }
}

// ============================================================
// d7: o slice per (h,b): agg = g1*(r-WM)+b1*A2;  o = agg@Wv + A2*bv
// ============================================================
__global__ __launch_bounds__(192) void k_att_o(
    const float* __restrict__ g1, const float* __restrict__ b1,
    const float* __restrict__ Wv, const float* __restrict__ bv,
    float* __restrict__ ws)
{
  const int h = blockIdx.x;
  const int b = blockIdx.y;
  const int t = threadIdx.x;

  __shared__ __align__(16) float agg_l[DD];
  __shared__ float red[8][25];
  __shared__ float a2wm[2];

  if (t == 0) {
    float a = 0.f;
#pragma unroll
    for (int c = 0; c < 4; ++c) a += ws[WS_A2P + ((size_t)b * 4 + c) * HH + h];
    a2wm[0] = a;
  }
  if (t == 1) {
    float w = 0.f;
#pragma unroll
    for (int c = 0; c < 4; ++c) w += ws[WS_WMP + ((size_t)b * 4 + c) * HH + h];
    a2wm[1] = w;
  }
  __syncthreads();
  const float A2 = a2wm[0], WM = a2wm[1];
  const float* R = ws + WS_T + ((size_t)b * HH + h) * DD;
  for (int i = t; i < DD; i += 192)
    agg_l[i] = g1[i] * (R[i] - WM) + b1[i] * A2;
  __syncthreads();

  const int oc = t % 24, ks = t / 24;
  const float* wv = Wv + (size_t)(ks * 96) * DD + h * HD24 + oc;
  const float* ag = agg_l + ks * 96;
  float a0 = 0.f, a1 = 0.f, a2 = 0.f, a3 = 0.f;
#pragma unroll 4
  for (int d = 0; d < 96; d += 4) {
    a0 += ag[d + 0] * wv[(size_t)(d + 0) * DD];
    a1 += ag[d + 1] * wv[(size_t)(d + 1) * DD];
    a2 += ag[d + 2] * wv[(size_t)(d + 2) * DD];
    a3 += ag[d + 3] * wv[(size_t)(d + 3) * DD];
  }
  red[ks][oc] = (a0 + a1) + (a2 + a3);
  __syncthreads();
  if (t < 24) {
    float o = A2 * bv[h * HD24 + t];
#pragma unroll
    for (int k = 0; k < 8; ++k) o += red[k][t];
    ws[WS_O + (size_t)b * DD + h * HD24 + t] = o;
  }
}

// ============================================================
// d8: c1 = x_cls + o @ projW + projb  (+ LN2 partial stats). grid (12, 64)
// ============================================================
__global__ __launch_bounds__(256) void k_proj2(
    const float* __restrict__ x_cls,
    const float* __restrict__ projW, const float* __restrict__ projb,
    float* __restrict__ ws)
{
  const int b = blockIdx.y;
  const int oc0 = blockIdx.x * 64;
  const int t = threadIdx.x;

  __shared__ __align__(16) float o_l[DD];
  __shared__ float red4[4][64];

  for (int i = t; i < DD; i += 256) o_l[i] = ws[WS_O + (size_t)b * DD + i];
  __syncthreads();

  const int oc = t & 63, ks = t >> 6;
  const float* wp = projW + (size_t)(ks * 192) * DD + oc0 + oc;
  const float* op = o_l + ks * 192;
  float a0 = 0.f, a1 = 0.f, a2 = 0.f, a3 = 0.f;
#pragma unroll 4
  for (int d = 0; d < 192; d += 4) {
    a0 += op[d + 0] * wp[(size_t)(d + 0) * DD];
    a1 += op[d + 1] * wp[(size_t)(d + 1) * DD];
    a2 += op[d + 2] * wp[(size_t)(d + 2) * DD];
    a3 += op[d + 3] * wp[(size_t)(d + 3) * DD];
  }
  red4[ks][oc] = (a0 + a1) + (a2 + a3);
  __syncthreads();
  if (t < 64) {
    int ocg = oc0 + t;
    float c1 = red4[0][t] + red4[1][t] + red4[2][t] + red4[3][t]
             + projb[ocg] + x_cls[(size_t)b * DD + ocg];
    ws[WS_C1 + (size_t)b * DD + ocg] = c1;
    float cs = c1, cq = c1 * c1;
#pragma unroll
    for (int off = 1; off < 64; off <<= 1) { cs += __shfl_xor(cs, off); cq += __shfl_xor(cq, off); }
    if (t == 0) {
      ws[WS_PS + ((size_t)b * 12 + blockIdx.x) * 2 + 0] = cs;
      ws[WS_PS + ((size_t)b * 12 + blockIdx.x) * 2 + 1] = cq;
    }
  }
}

// ============================================================
// d9: fc1 (grouped, LN2 fused) + exact GELU + channel shuffle. grid 96.
// ============================================================
__global__ __launch_bounds__(256) void k_fc1(
    const float* __restrict__ fc1W, const float* __restrict__ fc1b,
    const float* __restrict__ g2, const float* __restrict__ b2,
    float* __restrict__ ws)
{
  const int g = blockIdx.x / 48;
  const int oc0 = (blockIdx.x % 48) * 32;
  const int t = threadIdx.x;
  const int txo = t & 7, tyb = t >> 3;

  __shared__ float y_s[64][65];
  __shared__ float w_s[32][65];
  __shared__ float mv[64][2];

  if (t < 64) {
    float s = 0.f, q = 0.f;
#pragma unroll
    for (int p = 0; p < 12; ++p) {
      s += ws[WS_PS + ((size_t)t * 12 + p) * 2 + 0];
      q += ws[WS_PS + ((size_t)t * 12 + p) * 2 + 1];
    }
    float mu = s * (1.f / DD);
    mv[t][0] = mu;
    mv[t][1] = rsqrtf(q * (1.f / DD) - mu * mu + LNEPS);
  }
  __syncthreads();

  float acc[2][4];
#pragma unroll
  for (int i = 0; i < 2; ++i)
#pragma unroll
    for (int j = 0; j < 4; ++j) acc[i][j] = 0.f;

#pragma unroll 1
  for (int kc = 0; kc < 6; ++kc) {
    {
      int r = t >> 2;
      float mu = mv[r][0], rs = mv[r][1];
#pragma unroll
      for (int p = 0; p < 4; ++p) {
        int c = (t & 3) * 4 + p * 16;
        int gc = g * 384 + kc * 64 + c;
        float4 v = *(const float4*)(ws + WS_C1 + (size_t)r * DD + gc);
        float4 gg = *(const float4*)(g2 + gc);
        float4 bb = *(const float4*)(b2 + gc);
        y_s[r][c+0] = (v.x - mu) * rs * gg.x + bb.x;
        y_s[r][c+1] = (v.y - mu) * rs * gg.y + bb.y;
        y_s[r][c+2] = (v.z - mu) * rs * gg.z + bb.z;
        y_s[r][c+3] = (v.w - mu) * rs * gg.w + bb.w;
      }
      int rw = t >> 3;
#pragma unroll
      for (int p = 0; p < 2; ++p) {
        int c = (t & 7) * 4 + p * 32;
        float4 w = *(const float4*)(fc1W + ((size_t)(g * 1536 + oc0 + rw)) * 384 + kc * 64 + c);
        w_s[rw][c+0] = w.x; w_s[rw][c+1] = w.y; w_s[rw][c+2] = w.z; w_s[rw][c+3] = w.w;
      }
    }
    __syncthreads();
#pragma unroll 4
    for (int kk = 0; kk < 64; ++kk) {
      float y0 = y_s[2*tyb+0][kk], y1 = y_s[2*tyb+1][kk];
      float w0 = w_s[4*txo+0][kk], w1 = w_s[4*txo+1][kk];
      float w2 = w_s[4*txo+2][kk], w3 = w_s[4*txo+3][kk];
      acc[0][0] += y0*w0; acc[0][1] += y0*w1; acc[0][2] += y0*w2; acc[0][3] += y0*w3;
      acc[1][0] += y1*w0; acc[1][1] += y1*w1; acc[1][2] += y1*w2; acc[1][3] += y1*w3;
    }
    __syncthreads();
  }

  float* H2 = ws + WS_H2;
#pragma unroll
  for (int i = 0; i < 2; ++i) {
    int bb = 2 * tyb + i;
#pragma unroll
    for (int j = 0; j < 4; ++j) {
      int oc = oc0 + 4 * txo + j;
      float v = acc[i][j] + fc1b[g * 1536 + oc];
      v = 0.5f * v * (1.f + erff(v * 0.70710678118654752f));
      H2[(size_t)bb * HIDN + (oc & 1) * 1536 + g * 768 + (oc >> 1)] = v;
    }
  }
}

// ============================================================
// d10: fc2 (grouped, k-split 4). grid (12, 4, 2).
// ============================================================
__global__ __launch_bounds__(256) void k_fc2(
    const float* __restrict__ fc2W, float* __restrict__ ws)
{
  const int oc0 = blockIdx.x * 32;
  const int kq = blockIdx.y;
  const int g = blockIdx.z;
  const int t = threadIdx.x;
  const int txo = t & 7, tyb = t >> 3;

  __shared__ float h_s[64][65];
  __shared__ float w_s[32][65];

  float acc[2][4];
#pragma unroll
  for (int i = 0; i < 2; ++i)
#pragma unroll
    for (int j = 0; j < 4; ++j) acc[i][j] = 0.f;

  const float* H2 = ws + WS_H2;

#pragma unroll 1
  for (int kc = 0; kc < 6; ++kc) {
    {
      int r = t >> 2;
#pragma unroll
      for (int p = 0; p < 4; ++p) {
        int c = (t & 3) * 4 + p * 16;
        float4 v = *(const float4*)(H2 + (size_t)r * HIDN + g * 1536 + kq * 384 + kc * 64 + c);
        h_s[r][c+0] = v.x; h_s[r][c+1] = v.y; h_s[r][c+2] = v.z; h_s[r][c+3] = v.w;
      }
      int rw = t >> 3;
#pragma unroll
      for (int p = 0; p < 2; ++p) {
        int c = (t & 7) * 4 + p * 32;
        float4 w = *(const float4*)(fc2W + ((size_t)(g * 384 + oc0 + rw)) * 1536 + kq * 384 + kc * 64 + c);
        w_s[rw][c+0] = w.x; w_s[rw][c+1] = w.y; w_s[rw][c+2] = w.z; w_s[rw][c+3] = w.w;
      }
    }
    __syncthreads();
#pragma unroll 4
    for (int kk = 0; kk < 64; ++kk) {
      float y0 = h_s[2*tyb+0][kk], y1 = h_s[2*tyb+1][kk];
      float w0 = w_s[4*txo+0][kk], w1 = w_s[4*txo+1][kk];
      float w2 = w_s[4*txo+2][kk], w3 = w_s[4*txo+3][kk];
      acc[0][0] += y0*w0; acc[0][1] += y0*w1; acc[0][2] += y0*w2; acc[0][3] += y0*w3;
      acc[1][0] += y1*w0; acc[1][1] += y1*w1; acc[1][2] += y1*w2; acc[1][3] += y1*w3;
    }
    __syncthreads();
  }

  float* ZP = ws + WS_ZP + (size_t)kq * BB * DD;
#pragma unroll
  for (int i = 0; i < 2; ++i)
#pragma unroll
    for (int j = 0; j < 4; ++j)
      ZP[(size_t)(2 * tyb + i) * DD + g * 384 + oc0 + 4 * txo + j] = acc[i][j];
}

// ============================================================
// d11: out_cls = c1 + fc2_b + sum partials
// ============================================================
__global__ __launch_bounds__(256) void k_final(
    const float* __restrict__ fc2b, float* __restrict__ out, const float* __restrict__ ws)
{
  int idx = blockIdx.x * 256 + threadIdx.x;
  int d = idx % DD;
  float v = ws[WS_C1 + idx] + fc2b[d];
#pragma unroll
  for (int kq = 0; kq < 4; ++kq) v += ws[WS_ZP + (size_t)kq * BB * DD + idx];
  out[idx] = v;
}

extern "C" void kernel_launch(void* const* d_in, const int* in_sizes, int n_in,
                              void* d_out, int out_size, void* d_ws, size_t ws_size,
                              hipStream_t stream)
{
  (void)in_sizes; (void)n_in; (void)out_size;
  const float* x_cls = (const float*)d_in[0];
  const float* x_img = (const float*)d_in[1];
  const float* ln1_g = (const float*)d_in[2];
  const float* ln1_b = (const float*)d_in[3];
  const float* Wq    = (const float*)d_in[4];
  const float* bq    = (const float*)d_in[5];
  const float* Wk    = (const float*)d_in[6];
  const float* bk    = (const float*)d_in[7];
  const float* Wv    = (const float*)d_in[8];
  const float* bv    = (const float*)d_in[9];
  const float* w1W   = (const float*)d_in[10];
  const float* w1b   = (const float*)d_in[11];
  const float* w2W   = (const float*)d_in[12];
  const float* w2b   = (const float*)d_in[13];
  const float* projW = (const float*)d_in[14];
  const float* projb = (const float*)d_in[15];
  const float* ln2_g = (const float*)d_in[16];
  const float* ln2_b = (const float*)d_in[17];
  const float* fc1W  = (const float*)d_in[18];
  const float* fc1b  = (const float*)d_in[19];
  const float* fc2W  = (const float*)d_in[20];
  const float* fc2b  = (const float*)d_in[21];
  float* out = (float*)d_out;
  float* ws  = (float*)d_ws;

  const int ksplit = (ws_size >= (size_t)WS_KSEND * 4) ? 1 : 0;

  k_q    <<<dim3(12, 64), dim3(256), 0, stream>>>(x_cls, ln1_g, ln1_b, Wq, bq, ws);
  k_gqk  <<<dim3(6, 64),  dim3(256), 0, stream>>>(ln1_g, ln1_b, Wk, w1W, ws);
  k_main1<<<dim3(13, 64, ksplit ? 2 : 1), dim3(256), 0, stream>>>(x_cls, x_img, ws);
  k_sm_a <<<dim3(4, 64),  dim3(256), 0, stream>>>(bk, w1W, w1b, ws, ksplit);
  k_sm_b <<<dim3(4, 64),  dim3(256), 0, stream>>>(w2W, w2b, ws);
  k_wsum <<<dim3(12, 64), dim3(512), 0, stream>>>(x_cls, x_img, out, ws);
  k_att_o<<<dim3(32, 64), dim3(192), 0, stream>>>(ln1_g, ln1_b, Wv, bv, ws);
  k_proj2<<<dim3(12, 64), dim3(256), 0, stream>>>(x_cls, projW, projb, ws);
  k_fc1  <<<dim3(96),     dim3(256), 0, stream>>>(fc1W, fc1b, ln2_g, ln2_b, ws);
  k_fc2  <<<dim3(12, 4, 2), dim3(256), 0, stream>>>(fc2W, ws);
  k_final<<<dim3(192),    dim3(256), 0, stream>>>(fc2b, out, ws);
}

// Round 15
// 301.416 us; speedup vs baseline: 1.0413x; 1.0413x over previous
//
#include <hip/hip_runtime.h>
#include <hip/hip_bf16.h>
#include <math.h>

#define BB   64
#define NN   784
#define DD   768
#define HH   32
#define HD24 24
#define MM   785
#define HIDN 3072
#define QSCALE 0.20412414523193154f
#define LNEPS 1e-6f

// ---- workspace layout (float offsets) ----
#define WS_Q     0          // [64][768]
#define WS_RS    49152      // [64][800]
#define WS_RM    100352     // [64][800]
#define WS_S1P   151552     // [64][6][32]
#define WS_BQP   163840     // [64][6][32]
#define WS_LMX   176128     // [64][4][32]
#define WS_LSM   184320
#define WS_A2P   192512
#define WS_WMP   200704
#define WS_PS    208896     // [64][12][2]
#define WS_C1    210432     // [64][768]
#define WS_H2    259584     // [64][3072]
#define WS_O     456192     // [64][768]
#define WS_E     505344     // GQB bf16-frag (d2-d3), then E/W [64][32][800] (d4-d6)
#define WS_T     2143744    // t [64][785][32] (d3-d4), then r [64][32][768] (d6-d7)
#define WS_T2    3751424    // t-half-2 (d3-d4) [ksplit only]
#define WS_SLQ   5359104    // [64][2][800][2] partial LN stats (ksplit only)
#define WS_KSEND 5563904    // gate: ksplit needs ws_size >= this * 4 bytes
#define WS_ZP    0          // [4][64][768] overlay (d10-d11)

typedef __attribute__((ext_vector_type(8))) short bf16x8;
typedef __attribute__((ext_vector_type(4))) float f32x4;

__device__ __forceinline__ unsigned packbf(float a, float b) {
  union { __hip_bfloat162 h2; unsigned u; } cv;
  cv.h2 = __float22bfloat162_rn(make_float2(a, b));
  return cv.u;
}

// ============================================================
// d1: q = (LN(x_cls) @ Wq + bq) * QSCALE     grid (12, 64)
// ============================================================
__global__ __launch_bounds__(256) void k_q(
    const float* __restrict__ x_cls,
    const float* __restrict__ g1, const float* __restrict__ b1,
    const float* __restrict__ Wq, const float* __restrict__ bq,
    float* __restrict__ ws)
{
  const int b = blockIdx.y;
  const int oc0 = blockIdx.x * 64;
  const int t = threadIdx.x;
  const int lane = t & 63, wid = t >> 6;

  __shared__ __align__(16) float nc_l[DD];
  __shared__ float red4[4][64];
  __shared__ float rS[4], rQ[4];
  __shared__ float musd[2];

  float xv[3];
  float s = 0.f, q2 = 0.f;
#pragma unroll
  for (int k = 0; k < 3; ++k) {
    float v = x_cls[(size_t)b * DD + t + 256 * k];
    xv[k] = v; s += v; q2 += v * v;
  }
#pragma unroll
  for (int off = 1; off < 64; off <<= 1) { s += __shfl_xor(s, off); q2 += __shfl_xor(q2, off); }
  if (lane == 0) { rS[wid] = s; rQ[wid] = q2; }
  __syncthreads();
  if (t == 0) {
    float ss = rS[0] + rS[1] + rS[2] + rS[3];
    float qq = rQ[0] + rQ[1] + rQ[2] + rQ[3];
    float mu = ss * (1.f / DD);
    musd[0] = mu; musd[1] = rsqrtf(qq * (1.f / DD) - mu * mu + LNEPS);
  }
  __syncthreads();
  {
    float mu = musd[0], rs = musd[1];
#pragma unroll
    for (int k = 0; k < 3; ++k) {
      int d = t + 256 * k;
      nc_l[d] = (xv[k] - mu) * rs * g1[d] + b1[d];
    }
  }
  __syncthreads();

  const int oc = t & 63, ks = t >> 6;
  const float* wp = Wq + (size_t)(ks * 192) * DD + oc0 + oc;
  const float* ncp = nc_l + ks * 192;
  float a0 = 0.f, a1 = 0.f, a2 = 0.f, a3 = 0.f;
#pragma unroll 4
  for (int d = 0; d < 192; d += 4) {
    a0 += ncp[d + 0] * wp[(size_t)(d + 0) * DD];
    a1 += ncp[d + 1] * wp[(size_t)(d + 1) * DD];
    a2 += ncp[d + 2] * wp[(size_t)(d + 2) * DD];
    a3 += ncp[d + 3] * wp[(size_t)(d + 3) * DD];
  }
  red4[ks][oc] = (a0 + a1) + (a2 + a3);
  __syncthreads();
  if (t < 64) {
    int ocg = oc0 + t;
    ws[WS_Q + (size_t)b * DD + ocg] =
        (red4[0][t] + red4[1][t] + red4[2][t] + red4[3][t] + bq[ocg]) * QSCALE;
  }
}

// ============================================================
// d2: gq = fold(T1, qk) ; write bf16 MFMA-B-fragment-swizzled GQB;
// partial s1, bqs.  grid (6 d-tiles of 128, 64)
// ============================================================
__global__ __launch_bounds__(256) void k_gqk(
    const float* __restrict__ g1, const float* __restrict__ b1,
    const float* __restrict__ Wk, const float* __restrict__ w1W,
    float* __restrict__ ws)
{
  const int b = blockIdx.y;
  const int d0 = blockIdx.x * 128;
  const int t = threadIdx.x;

  __shared__ __align__(16) float q_l[DD];
  __shared__ float T1[HH * HH];
  __shared__ float qk_l[128][33];
  __shared__ float pS[8][HH], pB[8][HH];

  for (int i = t; i < DD; i += 256) q_l[i] = ws[WS_Q + (size_t)b * DD + i];
  for (int i = t; i < HH * HH; i += 256) {
    int g = i >> 5, h = i & 31;
    T1[i] = w1W[i] + ((g == h) ? 1.f : 0.f);
  }
  __syncthreads();

  { // phase 1: qk[d][g]
    const int dl = t >> 1, gh = t & 1;
    const float4* wr = (const float4*)(Wk + (size_t)(d0 + dl) * DD + gh * 384);
    const float4* qr = (const float4*)(q_l + gh * 384);
#pragma unroll 4
    for (int gg = 0; gg < 16; ++gg) {
      float a = 0.f;
#pragma unroll
      for (int c = 0; c < 6; ++c) {
        float4 w = wr[gg * 6 + c];
        float4 p = qr[gg * 6 + c];
        a += w.x * p.x + w.y * p.y + w.z * p.z + w.w * p.w;
      }
      qk_l[dl][gh * 16 + gg] = a;
    }
  }
  __syncthreads();
  { // phase 2: mix + write bf16 swizzled GQB + partials
    const int h = t & 31, dg = t >> 5;
    float fb[16];
    float s1a = 0.f, bqa = 0.f;
#pragma unroll 2
    for (int dd = 0; dd < 16; ++dd) {
      int dl = dg * 16 + dd;
      float f = 0.f;
#pragma unroll 8
      for (int g = 0; g < HH; ++g) f += qk_l[dl][g] * T1[g * HH + h];
      float gq = g1[d0 + dl] * f;
      fb[dd] = gq;
      s1a += gq;
      bqa += b1[d0 + dl] * qk_l[dl][h];
    }
    const int kstep = (d0 >> 5) + (dg >> 1);
    const int nt = h >> 4;
    const int lane0 = (h & 15) + 32 * (dg & 1);
    uint4* GQB = (uint4*)(ws + WS_E) + (size_t)b * (24 * 2 * 64);
    GQB[(kstep * 2 + nt) * 64 + lane0] =
        make_uint4(packbf(fb[0], fb[1]), packbf(fb[2], fb[3]),
                   packbf(fb[4], fb[5]), packbf(fb[6], fb[7]));
    GQB[(kstep * 2 + nt) * 64 + lane0 + 16] =
        make_uint4(packbf(fb[8], fb[9]), packbf(fb[10], fb[11]),
                   packbf(fb[12], fb[13]), packbf(fb[14], fb[15]));
    pS[dg][h] = s1a; pB[dg][h] = bqa;
  }
  __syncthreads();
  if (t < HH) {
    float s = 0.f, bq = 0.f;
#pragma unroll
    for (int k = 0; k < 8; ++k) { s += pS[k][t]; bq += pB[k][t]; }
    ws[WS_S1P + ((size_t)b * 6 + blockIdx.x) * HH + t] = s;
    ws[WS_BQP + ((size_t)b * 6 + blockIdx.x) * HH + t] = bq;
  }
}

// ============================================================
// d3: big pass 1 (MFMA, lean). 64 rows/block, grid (13, 64, nz), 4 waves.
// ============================================================
__global__ __launch_bounds__(256) void k_main1(
    const float* __restrict__ x_cls, const float* __restrict__ x_img,
    float* __restrict__ ws)
{
  const int b = blockIdx.y;
  const int m0 = blockIdx.x * 64;
  const int nz = gridDim.z;
  const int kh = blockIdx.z;
  const int t = threadIdx.x;
  const int w = t >> 6;
  const int l = t & 63;
  const int lg = l >> 4;       // k-octet within 32-step
  const int lm = l & 15;       // A-row / B-col within 16-tile

  const uint4* GQ = (const uint4*)(ws + WS_E) + (size_t)b * (24 * 2 * 64);

  const int arow = m0 + w * 16 + lm;
  const bool av = (arow < MM);
  const int arc = av ? arow : 0;
  const float* asrc = (arc == 0) ? (x_cls + (size_t)b * DD)
                                 : (x_img + ((size_t)b * NN + (arc - 1)) * DD);
  const int nk = 24 / nz;
  const int k0 = kh * nk;

  f32x4 acc0 = {0.f, 0.f, 0.f, 0.f};
  f32x4 acc1 = {0.f, 0.f, 0.f, 0.f};
  float sl = 0.f, sq = 0.f;

#pragma unroll 4
  for (int kst = k0; kst < k0 + nk; ++kst) {
    float4 a0 = make_float4(0.f, 0.f, 0.f, 0.f);
    float4 a1 = make_float4(0.f, 0.f, 0.f, 0.f);
    if (av) {
      a0 = *(const float4*)(asrc + kst * 32 + 8 * lg);
      a1 = *(const float4*)(asrc + kst * 32 + 8 * lg + 4);
    }
    sl += (a0.x + a0.y) + (a0.z + a0.w) + (a1.x + a1.y) + (a1.z + a1.w);
    sq += a0.x*a0.x + a0.y*a0.y + a0.z*a0.z + a0.w*a0.w
        + a1.x*a1.x + a1.y*a1.y + a1.z*a1.z + a1.w*a1.w;
    union { uint4 u; bf16x8 h; } ua, ub0, ub1;
    ua.u = make_uint4(packbf(a0.x, a0.y), packbf(a0.z, a0.w),
                      packbf(a1.x, a1.y), packbf(a1.z, a1.w));
    ub0.u = GQ[(kst * 2 + 0) * 64 + l];
    ub1.u = GQ[(kst * 2 + 1) * 64 + l];
    acc0 = __builtin_amdgcn_mfma_f32_16x16x32_bf16(ua.h, ub0.h, acc0, 0, 0, 0);
    acc1 = __builtin_amdgcn_mfma_f32_16x16x32_bf16(ua.h, ub1.h, acc1, 0, 0, 0);
  }

  sl += __shfl_xor(sl, 16); sl += __shfl_xor(sl, 32);
  sq += __shfl_xor(sq, 16); sq += __shfl_xor(sq, 32);
  if (lg == 0 && av) {
    if (nz == 1) {
      float mu = sl * (1.f / DD);
      float rs = rsqrtf(sq * (1.f / DD) - mu * mu + LNEPS);
      ws[WS_RS + (size_t)b * 800 + arow] = rs;
      ws[WS_RM + (size_t)b * 800 + arow] = rs * mu;
    } else {
      float* slq = ws + WS_SLQ + (((size_t)b * 2 + kh) * 800 + arow) * 2;
      slq[0] = sl; slq[1] = sq;
    }
  }

  float* tb = ws + (kh ? WS_T2 : WS_T) + (size_t)b * MM * HH;
#pragma unroll
  for (int r = 0; r < 4; ++r) {
    int row = m0 + w * 16 + 4 * lg + r;
    if (row < MM) {
      tb[(size_t)row * HH + lm] = acc0[r];
      tb[(size_t)row * HH + 16 + lm] = acc1[r];
    }
  }
}

// ============================================================
// d4: online softmax pass A. grid (4 m-chunks, 64).
// ============================================================
__global__ __launch_bounds__(256) void k_sm_a(
    const float* __restrict__ bk,
    const float* __restrict__ w1W, const float* __restrict__ w1b,
    float* __restrict__ ws, int ksplit)
{
  const int cx = blockIdx.x, b = blockIdx.y;
  const int t = threadIdx.x;
  const int lane = t & 63, wid = t >> 6;

  __shared__ float T1[HH * HH];
  __shared__ float s1_sh[HH], c0_sh[HH], bq_sh[HH];
  __shared__ float red[4][HH];
  __shared__ float lmax_sh[HH];

  for (int i = t; i < HH * HH; i += 256) {
    int g = i >> 5, h = i & 31;
    T1[i] = w1W[i] + ((g == h) ? 1.f : 0.f);
  }
  if (t < HH) {
    float s1v = 0.f, bqv = 0.f;
#pragma unroll
    for (int p = 0; p < 6; ++p) {
      s1v += ws[WS_S1P + ((size_t)b * 6 + p) * HH + t];
      bqv += ws[WS_BQP + ((size_t)b * 6 + p) * HH + t];
    }
    const float* qp = ws + WS_Q + (size_t)b * DD + t * HD24;
#pragma unroll
    for (int j = 0; j < HD24; ++j) bqv += bk[t * HD24 + j] * qp[j];
    s1_sh[t] = s1v; bq_sh[t] = bqv;
  }
  __syncthreads();
  if (t < HH) {
    float c0 = w1b[t];
#pragma unroll
    for (int g = 0; g < HH; ++g) c0 += T1[g * HH + t] * bq_sh[g];
    c0_sh[t] = c0;
  }
  __syncthreads();

  const int m = cx * 256 + t;
  const bool vm = (m < MM);
  float a1[HH];
  if (vm) {
    const float* tb = ws + WS_T + ((size_t)b * MM + m) * HH;
    const float* tb2 = ws + WS_T2 + ((size_t)b * MM + m) * HH;
    float rs, rm;
    if (ksplit) {
      const float* slq = ws + WS_SLQ + ((size_t)b * 2 * 800 + m) * 2;
      float sl = slq[0] + slq[(size_t)800 * 2];
      float sq = slq[1] + slq[(size_t)800 * 2 + 1];
      float mu = sl * (1.f / DD);
      rs = rsqrtf(sq * (1.f / DD) - mu * mu + LNEPS);
      rm = rs * mu;
      ws[WS_RS + (size_t)b * 800 + m] = rs;
      ws[WS_RM + (size_t)b * 800 + m] = rm;
    } else {
      rs = ws[WS_RS + (size_t)b * 800 + m];
      rm = ws[WS_RM + (size_t)b * 800 + m];
    }
#pragma unroll
    for (int q = 0; q < 8; ++q) {
      float4 tv = *(const float4*)(tb + q * 4);
      if (ksplit) {
        float4 t2 = *(const float4*)(tb2 + q * 4);
        tv.x += t2.x; tv.y += t2.y; tv.z += t2.z; tv.w += t2.w;
      }
      a1[4*q+0] = rs * tv.x - rm * s1_sh[4*q+0] + c0_sh[4*q+0];
      a1[4*q+1] = rs * tv.y - rm * s1_sh[4*q+1] + c0_sh[4*q+1];
      a1[4*q+2] = rs * tv.z - rm * s1_sh[4*q+2] + c0_sh[4*q+2];
      a1[4*q+3] = rs * tv.w - rm * s1_sh[4*q+3] + c0_sh[4*q+3];
    }
  } else {
#pragma unroll
    for (int h = 0; h < HH; ++h) a1[h] = -3.0e38f;
  }
#pragma unroll
  for (int h = 0; h < HH; ++h) {
    float v = a1[h];
#pragma unroll
    for (int off = 1; off < 64; off <<= 1) v = fmaxf(v, __shfl_xor(v, off));
    if (lane == 0) red[wid][h] = v;
  }
  __syncthreads();
  if (t < HH) {
    float v = fmaxf(fmaxf(red[0][t], red[1][t]), fmaxf(red[2][t], red[3][t]));
    lmax_sh[t] = v;
    ws[WS_LMX + ((size_t)b * 4 + cx) * HH + t] = v;
  }
  __syncthreads();
  float* E = ws + WS_E + (size_t)b * (HH * 800);
  if (vm) {
#pragma unroll
    for (int h = 0; h < HH; ++h) {
      float e = __expf(a1[h] - lmax_sh[h]);
      a1[h] = e;
      E[(size_t)h * 800 + m] = e;
    }
  } else {
#pragma unroll
    for (int h = 0; h < HH; ++h) a1[h] = 0.f;
  }
#pragma unroll
  for (int h = 0; h < HH; ++h) {
    float v = a1[h];
#pragma unroll
    for (int off = 1; off < 64; off <<= 1) v += __shfl_xor(v, off);
    if (lane == 0) red[wid][h] = v;
  }
  __syncthreads();
  if (t < HH)
    ws[WS_LSM + ((size_t)b * 4 + cx) * HH + t] = red[0][t] + red[1][t] + red[2][t] + red[3][t];
}

// ============================================================
// d5: softmax pass B. grid (4, 64).
// ============================================================
__global__ __launch_bounds__(256) void k_sm_b(
    const float* __restrict__ w2W, const float* __restrict__ w2b,
    float* __restrict__ ws)
{
  const int cx = blockIdx.x, b = blockIdx.y;
  const int t = threadIdx.x;
  const int lane = t & 63, wid = t >> 6;

  __shared__ __align__(16) float T2s[HH * HH];
  __shared__ float inv_sh[HH], w2b_sh[HH];
  __shared__ float red[4][HH];

  if (t < HH) {
    float l0 = ws[WS_LMX + ((size_t)b * 4 + 0) * HH + t];
    float l1 = ws[WS_LMX + ((size_t)b * 4 + 1) * HH + t];
    float l2 = ws[WS_LMX + ((size_t)b * 4 + 2) * HH + t];
    float l3 = ws[WS_LMX + ((size_t)b * 4 + 3) * HH + t];
    float gmax = fmaxf(fmaxf(l0, l1), fmaxf(l2, l3));
    float s = ws[WS_LSM + ((size_t)b * 4 + 0) * HH + t] * __expf(l0 - gmax)
            + ws[WS_LSM + ((size_t)b * 4 + 1) * HH + t] * __expf(l1 - gmax)
            + ws[WS_LSM + ((size_t)b * 4 + 2) * HH + t] * __expf(l2 - gmax)
            + ws[WS_LSM + ((size_t)b * 4 + 3) * HH + t] * __expf(l3 - gmax);
    float lcx = (cx == 0) ? l0 : (cx == 1) ? l1 : (cx == 2) ? l2 : l3;
    inv_sh[t] = __expf(lcx - gmax) / s;
    w2b_sh[t] = w2b[t];
  }
  __syncthreads();
  for (int i = t; i < HH * HH; i += 256) {
    int g = i >> 5, h = i & 31;
    T2s[i] = (w2W[i] + ((g == h) ? 1.f : 0.f)) * inv_sh[g];
  }
  __syncthreads();

  const int m = cx * 256 + t;
  float* E = ws + WS_E + (size_t)b * (HH * 800);
  float4 av[8];
#pragma unroll
  for (int q = 0; q < 8; ++q) av[q] = make_float4(0.f,0.f,0.f,0.f);
  float rm = 0.f;
  if (m < MM) {
    float rs = ws[WS_RS + (size_t)b * 800 + m];
    rm = ws[WS_RM + (size_t)b * 800 + m];
#pragma unroll 4
    for (int g = 0; g < HH; ++g) {
      float eg = E[(size_t)g * 800 + m];
#pragma unroll
      for (int q = 0; q < 8; ++q) {
        float4 t2 = *(const float4*)&T2s[g * HH + q * 4];
        av[q].x += eg * t2.x; av[q].y += eg * t2.y;
        av[q].z += eg * t2.z; av[q].w += eg * t2.w;
      }
    }
#pragma unroll
    for (int q = 0; q < 8; ++q) {
      av[q].x += w2b_sh[q*4+0]; av[q].y += w2b_sh[q*4+1];
      av[q].z += w2b_sh[q*4+2]; av[q].w += w2b_sh[q*4+3];
      E[(size_t)(q*4+0) * 800 + m] = av[q].x * rs;
      E[(size_t)(q*4+1) * 800 + m] = av[q].y * rs;
      E[(size_t)(q*4+2) * 800 + m] = av[q].z * rs;
      E[(size_t)(q*4+3) * 800 + m] = av[q].w * rs;
    }
  } else if (m < 800) {
#pragma unroll
    for (int h = 0; h < HH; ++h) E[(size_t)h * 800 + m] = 0.f;
  }
#pragma unroll
  for (int h = 0; h < HH; ++h) {
    float v = ((const float*)&av[h >> 2])[h & 3];
#pragma unroll
    for (int off = 1; off < 64; off <<= 1) v += __shfl_xor(v, off);
    if (lane == 0) red[wid][h] = v;
  }
  __syncthreads();
  if (t < HH)
    ws[WS_A2P + ((size_t)b * 4 + cx) * HH + t] = red[0][t] + red[1][t] + red[2][t] + red[3][t];
  __syncthreads();
#pragma unroll
  for (int h = 0; h < HH; ++h) {
    float v = ((const float*)&av[h >> 2])[h & 3] * rm;
#pragma unroll
    for (int off = 1; off < 64; off <<= 1) v += __shfl_xor(v, off);
    if (lane == 0) red[wid][h] = v;
  }
  __syncthreads();
  if (t < HH)
    ws[WS_WMP + ((size_t)b * 4 + cx) * HH + t] = red[0][t] + red[1][t] + red[2][t] + red[3][t];
}

// ============================================================
// d6: r[b][h][d] = sum_m w[h][m] * u[m][d]  + fused x_img->out copy.
// 512 thr, 8 waves (m-halves in-block), LDS r-combine. grid (12, 64).
// Alternating 2-buffer w-tile per half -> ONE barrier per chunk.
// ============================================================
__global__ __launch_bounds__(512) void k_wsum(
    const float* __restrict__ x_cls, const float* __restrict__ x_img,
    float* __restrict__ out, float* __restrict__ ws)
{
  const int b = blockIdx.y;
  const int d0 = blockIdx.x * 64;
  const int t = threadIdx.x;
  const int wv = t >> 6;
  const int mh = wv >> 2;          // m-half (0/1)
  const int hw = wv & 3;           // head-quarter AND copy-row-owner
  const int hb = hw * 8;
  const int dseg = t & 15;
  const int msub = (t >> 4) & 3;
  const int mcBeg = mh * 13;
  const int mcN = 13 - mh;         // 13 or 12 chunks

  __shared__ __align__(16) float w_s[2][2][HH][36];   // [half][buf]
  __shared__ __align__(16) float r_s[HH][68];

  const float* W = ws + WS_E + (size_t)b * (HH * 800);
  float* out_img = out + (size_t)BB * DD;

  const int sh = t >> 8;           // staging half (== mh)
  const int si = t & 255;
  const int shN = 13 - sh;

  float acc[8][4];
#pragma unroll
  for (int j = 0; j < 8; ++j)
#pragma unroll
    for (int c = 0; c < 4; ++c) acc[j][c] = 0.f;

  float4 pu[8], pun[8];
  float4 pwn;

  auto LOADU = [&](int j, float4* dst) {
#pragma unroll
    for (int i = 0; i < 8; ++i) {
      int m = (mcBeg + j) * 32 + msub * 8 + i;
      if (j < mcN && m < MM) {
        const float* src = (m == 0) ? (x_cls + (size_t)b * DD)
                                    : (x_img + ((size_t)b * NN + (m - 1)) * DD);
        dst[i] = *(const float4*)(src + d0 + dseg * 4);
      } else dst[i] = make_float4(0.f,0.f,0.f,0.f);
    }
  };

  LOADU(0, pu);
  {
    float4 pw = *(const float4*)(W + (size_t)(si >> 3) * 800 + (sh * 13) * 32 + (si & 7) * 4);
    *(float4*)&w_s[sh][0][si >> 3][(si & 7) * 4] = pw;
  }
  __syncthreads();

  for (int j = 0; j < 13; ++j) {
    if (j + 1 < 13) {
      if (j + 1 < shN)
        pwn = *(const float4*)(W + (size_t)(si >> 3) * 800 + (sh * 13 + j + 1) * 32 + (si & 7) * 4);
      LOADU(j + 1, pun);
    }
    if (j < mcN) {
      const float (*wc)[36] = w_s[mh][j & 1];
#pragma unroll
      for (int jj = 0; jj < 8; ++jj) {
        float4 wA = *(const float4*)&wc[hb + jj][msub * 8];
        float4 wB = *(const float4*)&wc[hb + jj][msub * 8 + 4];
        float wv0 = wA.x, wv1 = wA.y, wv2 = wA.z, wv3 = wA.w;
        float wv4 = wB.x, wv5 = wB.y, wv6 = wB.z, wv7 = wB.w;
        acc[jj][0] += wv0*pu[0].x + wv1*pu[1].x + wv2*pu[2].x + wv3*pu[3].x
                    + wv4*pu[4].x + wv5*pu[5].x + wv6*pu[6].x + wv7*pu[7].x;
        acc[jj][1] += wv0*pu[0].y + wv1*pu[1].y + wv2*pu[2].y + wv3*pu[3].y
                    + wv4*pu[4].y + wv5*pu[5].y + wv6*pu[6].y + wv7*pu[7].y;
        acc[jj][2] += wv0*pu[0].z + wv1*pu[1].z + wv2*pu[2].z + wv3*pu[3].z
                    + wv4*pu[4].z + wv5*pu[5].z + wv6*pu[6].z + wv7*pu[7].z;
        acc[jj][3] += wv0*pu[0].w + wv1*pu[1].w + wv2*pu[2].w + wv3*pu[3].w
                    + wv4*pu[4].w + wv5*pu[5].w + wv6*pu[6].w + wv7*pu[7].w;
      }
      // fused copy-out of chunk j: wave-quarter hw stores subrows {2hw, 2hw+1}
#pragma unroll
      for (int i = 0; i < 8; ++i) {
        if ((i >> 1) == hw) {
          int m = (mcBeg + j) * 32 + msub * 8 + i;
          if (m >= 1 && m < MM)
            *(float4*)(out_img + ((size_t)b * NN + (m - 1)) * DD + d0 + dseg * 4) = pu[i];
        }
      }
    }
    if (j + 1 < 13) {
      if (j + 1 < shN)
        *(float4*)&w_s[sh][(j + 1) & 1][si >> 3][(si & 7) * 4] = pwn;
#pragma unroll
      for (int i = 0; i < 8; ++i) pu[i] = pun[i];
    }
    __syncthreads();   // single barrier: separates iter-j reads of buf[j&1]
                       // from iter-(j+1) writes of buf[j&1]; makes buf[(j+1)&1] visible
  }

  // reduce over msub (lanes 16, 32 apart)
#pragma unroll
  for (int j = 0; j < 8; ++j)
#pragma unroll
    for (int c = 0; c < 4; ++c) {
      float v = acc[j][c];
      v += __shfl_xor(v, 16);
      v += __shfl_xor(v, 32);
      acc[j][c] = v;
    }
  // cross-half combine via LDS
  if (mh == 1 && msub == 0) {
#pragma unroll
    for (int j = 0; j < 8; ++j)
      *(float4*)&r_s[hb + j][dseg * 4] =
          make_float4(acc[j][0], acc[j][1], acc[j][2], acc[j][3]);
  }
  __syncthreads();
  if (mh == 0 && msub == 0) {
    float* R = ws + WS_T + (size_t)b * HH * DD;
#pragma unroll
    for (int j = 0; j < 8; ++j) {
      float4 rv = *(const float4*)&r_s[hb + j][dseg * 4];
      *(float4*)(R + (size_t)(hb + j) * DD + d0 + dseg * 4) =
          make_float4(acc[j][0] + rv.x, acc[j][1] + rv.y,
                      acc[j][2] + rv.z, acc[j][3] + rv.w);
    }
  }
}

// ============================================================
// d7: o slice per (h,b): agg = g1*(r-WM)+b1*A2;  o = agg@Wv + A2*bv
// ============================================================
__global__ __launch_bounds__(192) void k_att_o(
    const float* __restrict__ g1, const float* __restrict__ b1,
    const float* __restrict__ Wv, const float* __restrict__ bv,
    float* __restrict__ ws)
{
  const int h = blockIdx.x;
  const int b = blockIdx.y;
  const int t = threadIdx.x;

  __shared__ __align__(16) float agg_l[DD];
  __shared__ float red[8][25];
  __shared__ float a2wm[2];

  if (t == 0) {
    float a = 0.f;
#pragma unroll
    for (int c = 0; c < 4; ++c) a += ws[WS_A2P + ((size_t)b * 4 + c) * HH + h];
    a2wm[0] = a;
  }
  if (t == 1) {
    float w = 0.f;
#pragma unroll
    for (int c = 0; c < 4; ++c) w += ws[WS_WMP + ((size_t)b * 4 + c) * HH + h];
    a2wm[1] = w;
  }
  __syncthreads();
  const float A2 = a2wm[0], WM = a2wm[1];
  const float* R = ws + WS_T + ((size_t)b * HH + h) * DD;
  for (int i = t; i < DD; i += 192)
    agg_l[i] = g1[i] * (R[i] - WM) + b1[i] * A2;
  __syncthreads();

  const int oc = t % 24, ks = t / 24;
  const float* wv = Wv + (size_t)(ks * 96) * DD + h * HD24 + oc;
  const float* ag = agg_l + ks * 96;
  float a0 = 0.f, a1 = 0.f, a2 = 0.f, a3 = 0.f;
#pragma unroll 4
  for (int d = 0; d < 96; d += 4) {
    a0 += ag[d + 0] * wv[(size_t)(d + 0) * DD];
    a1 += ag[d + 1] * wv[(size_t)(d + 1) * DD];
    a2 += ag[d + 2] * wv[(size_t)(d + 2) * DD];
    a3 += ag[d + 3] * wv[(size_t)(d + 3) * DD];
  }
  red[ks][oc] = (a0 + a1) + (a2 + a3);
  __syncthreads();
  if (t < 24) {
    float o = A2 * bv[h * HD24 + t];
#pragma unroll
    for (int k = 0; k < 8; ++k) o += red[k][t];
    ws[WS_O + (size_t)b * DD + h * HD24 + t] = o;
  }
}

// ============================================================
// d8: c1 = x_cls + o @ projW + projb  (+ LN2 partial stats). grid (12, 64)
// ============================================================
__global__ __launch_bounds__(256) void k_proj2(
    const float* __restrict__ x_cls,
    const float* __restrict__ projW, const float* __restrict__ projb,
    float* __restrict__ ws)
{
  const int b = blockIdx.y;
  const int oc0 = blockIdx.x * 64;
  const int t = threadIdx.x;

  __shared__ __align__(16) float o_l[DD];
  __shared__ float red4[4][64];

  for (int i = t; i < DD; i += 256) o_l[i] = ws[WS_O + (size_t)b * DD + i];
  __syncthreads();

  const int oc = t & 63, ks = t >> 6;
  const float* wp = projW + (size_t)(ks * 192) * DD + oc0 + oc;
  const float* op = o_l + ks * 192;
  float a0 = 0.f, a1 = 0.f, a2 = 0.f, a3 = 0.f;
#pragma unroll 4
  for (int d = 0; d < 192; d += 4) {
    a0 += op[d + 0] * wp[(size_t)(d + 0) * DD];
    a1 += op[d + 1] * wp[(size_t)(d + 1) * DD];
    a2 += op[d + 2] * wp[(size_t)(d + 2) * DD];
    a3 += op[d + 3] * wp[(size_t)(d + 3) * DD];
  }
  red4[ks][oc] = (a0 + a1) + (a2 + a3);
  __syncthreads();
  if (t < 64) {
    int ocg = oc0 + t;
    float c1 = red4[0][t] + red4[1][t] + red4[2][t] + red4[3][t]
             + projb[ocg] + x_cls[(size_t)b * DD + ocg];
    ws[WS_C1 + (size_t)b * DD + ocg] = c1;
    float cs = c1, cq = c1 * c1;
#pragma unroll
    for (int off = 1; off < 64; off <<= 1) { cs += __shfl_xor(cs, off); cq += __shfl_xor(cq, off); }
    if (t == 0) {
      ws[WS_PS + ((size_t)b * 12 + blockIdx.x) * 2 + 0] = cs;
      ws[WS_PS + ((size_t)b * 12 + blockIdx.x) * 2 + 1] = cq;
    }
  }
}

// ============================================================
// d9: fc1 (grouped, LN2 fused) + exact GELU + channel shuffle. grid 96.
// ============================================================
__global__ __launch_bounds__(256) void k_fc1(
    const float* __restrict__ fc1W, const float* __restrict__ fc1b,
    const float* __restrict__ g2, const float* __restrict__ b2,
    float* __restrict__ ws)
{
  const int g = blockIdx.x / 48;
  const int oc0 = (blockIdx.x % 48) * 32;
  const int t = threadIdx.x;
  const int txo = t & 7, tyb = t >> 3;

  __shared__ float y_s[64][65];
  __shared__ float w_s[32][65];
  __shared__ float mv[64][2];

  if (t < 64) {
    float s = 0.f, q = 0.f;
#pragma unroll
    for (int p = 0; p < 12; ++p) {
      s += ws[WS_PS + ((size_t)t * 12 + p) * 2 + 0];
      q += ws[WS_PS + ((size_t)t * 12 + p) * 2 + 1];
    }
    float mu = s * (1.f / DD);
    mv[t][0] = mu;
    mv[t][1] = rsqrtf(q * (1.f / DD) - mu * mu + LNEPS);
  }
  __syncthreads();

  float acc[2][4];
#pragma unroll
  for (int i = 0; i < 2; ++i)
#pragma unroll
    for (int j = 0; j < 4; ++j) acc[i][j] = 0.f;

#pragma unroll 1
  for (int kc = 0; kc < 6; ++kc) {
    {
      int r = t >> 2;
      float mu = mv[r][0], rs = mv[r][1];
#pragma unroll
      for (int p = 0; p < 4; ++p) {
        int c = (t & 3) * 4 + p * 16;
        int gc = g * 384 + kc * 64 + c;
        float4 v = *(const float4*)(ws + WS_C1 + (size_t)r * DD + gc);
        float4 gg = *(const float4*)(g2 + gc);
        float4 bb = *(const float4*)(b2 + gc);
        y_s[r][c+0] = (v.x - mu) * rs * gg.x + bb.x;
        y_s[r][c+1] = (v.y - mu) * rs * gg.y + bb.y;
        y_s[r][c+2] = (v.z - mu) * rs * gg.z + bb.z;
        y_s[r][c+3] = (v.w - mu) * rs * gg.w + bb.w;
      }
      int rw = t >> 3;
#pragma unroll
      for (int p = 0; p < 2; ++p) {
        int c = (t & 7) * 4 + p * 32;
        float4 w = *(const float4*)(fc1W + ((size_t)(g * 1536 + oc0 + rw)) * 384 + kc * 64 + c);
        w_s[rw][c+0] = w.x; w_s[rw][c+1] = w.y; w_s[rw][c+2] = w.z; w_s[rw][c+3] = w.w;
      }
    }
    __syncthreads();
#pragma unroll 4
    for (int kk = 0; kk < 64; ++kk) {
      float y0 = y_s[2*tyb+0][kk], y1 = y_s[2*tyb+1][kk];
      float w0 = w_s[4*txo+0][kk], w1 = w_s[4*txo+1][kk];
      float w2 = w_s[4*txo+2][kk], w3 = w_s[4*txo+3][kk];
      acc[0][0] += y0*w0; acc[0][1] += y0*w1; acc[0][2] += y0*w2; acc[0][3] += y0*w3;
      acc[1][0] += y1*w0; acc[1][1] += y1*w1; acc[1][2] += y1*w2; acc[1][3] += y1*w3;
    }
    __syncthreads();
  }

  float* H2 = ws + WS_H2;
#pragma unroll
  for (int i = 0; i < 2; ++i) {
    int bb = 2 * tyb + i;
#pragma unroll
    for (int j = 0; j < 4; ++j) {
      int oc = oc0 + 4 * txo + j;
      float v = acc[i][j] + fc1b[g * 1536 + oc];
      v = 0.5f * v * (1.f + erff(v * 0.70710678118654752f));
      H2[(size_t)bb * HIDN + (oc & 1) * 1536 + g * 768 + (oc >> 1)] = v;
    }
  }
}

// ============================================================
// d10: fc2 (grouped, k-split 4). grid (12, 4, 2).
// ============================================================
__global__ __launch_bounds__(256) void k_fc2(
    const float* __restrict__ fc2W, float* __restrict__ ws)
{
  const int oc0 = blockIdx.x * 32;
  const int kq = blockIdx.y;
  const int g = blockIdx.z;
  const int t = threadIdx.x;
  const int txo = t & 7, tyb = t >> 3;

  __shared__ float h_s[64][65];
  __shared__ float w_s[32][65];

  float acc[2][4];
#pragma unroll
  for (int i = 0; i < 2; ++i)
#pragma unroll
    for (int j = 0; j < 4; ++j) acc[i][j] = 0.f;

  const float* H2 = ws + WS_H2;

#pragma unroll 1
  for (int kc = 0; kc < 6; ++kc) {
    {
      int r = t >> 2;
#pragma unroll
      for (int p = 0; p < 4; ++p) {
        int c = (t & 3) * 4 + p * 16;
        float4 v = *(const float4*)(H2 + (size_t)r * HIDN + g * 1536 + kq * 384 + kc * 64 + c);
        h_s[r][c+0] = v.x; h_s[r][c+1] = v.y; h_s[r][c+2] = v.z; h_s[r][c+3] = v.w;
      }
      int rw = t >> 3;
#pragma unroll
      for (int p = 0; p < 2; ++p) {
        int c = (t & 7) * 4 + p * 32;
        float4 w = *(const float4*)(fc2W + ((size_t)(g * 384 + oc0 + rw)) * 1536 + kq * 384 + kc * 64 + c);
        w_s[rw][c+0] = w.x; w_s[rw][c+1] = w.y; w_s[rw][c+2] = w.z; w_s[rw][c+3] = w.w;
      }
    }
    __syncthreads();
#pragma unroll 4
    for (int kk = 0; kk < 64; ++kk) {
      float y0 = h_s[2*tyb+0][kk], y1 = h_s[2*tyb+1][kk];
      float w0 = w_s[4*txo+0][kk], w1 = w_s[4*txo+1][kk];
      float w2 = w_s[4*txo+2][kk], w3 = w_s[4*txo+3][kk];
      acc[0][0] += y0*w0; acc[0][1] += y0*w1; acc[0][2] += y0*w2; acc[0][3] += y0*w3;
      acc[1][0] += y1*w0; acc[1][1] += y1*w1; acc[1][2] += y1*w2; acc[1][3] += y1*w3;
    }
    __syncthreads();
  }

  float* ZP = ws + WS_ZP + (size_t)kq * BB * DD;
#pragma unroll
  for (int i = 0; i < 2; ++i)
#pragma unroll
    for (int j = 0; j < 4; ++j)
      ZP[(size_t)(2 * tyb + i) * DD + g * 384 + oc0 + 4 * txo + j] = acc[i][j];
}

// ============================================================
// d11: out_cls = c1 + fc2_b + sum partials
// ============================================================
__global__ __launch_bounds__(256) void k_final(
    const float* __restrict__ fc2b, float* __restrict__ out, const float* __restrict__ ws)
{
  int idx = blockIdx.x * 256 + threadIdx.x;
  int d = idx % DD;
  float v = ws[WS_C1 + idx] + fc2b[d];
#pragma unroll
  for (int kq = 0; kq < 4; ++kq) v += ws[WS_ZP + (size_t)kq * BB * DD + idx];
  out[idx] = v;
}

extern "C" void kernel_launch(void* const* d_in, const int* in_sizes, int n_in,
                              void* d_out, int out_size, void* d_ws, size_t ws_size,
                              hipStream_t stream)
{
  (void)in_sizes; (void)n_in; (void)out_size;
  const float* x_cls = (const float*)d_in[0];
  const float* x_img = (const float*)d_in[1];
  const float* ln1_g = (const float*)d_in[2];
  const float* ln1_b = (const float*)d_in[3];
  const float* Wq    = (const float*)d_in[4];
  const float* bq    = (const float*)d_in[5];
  const float* Wk    = (const float*)d_in[6];
  const float* bk    = (const float*)d_in[7];
  const float* Wv    = (const float*)d_in[8];
  const float* bv    = (const float*)d_in[9];
  const float* w1W   = (const float*)d_in[10];
  const float* w1b   = (const float*)d_in[11];
  const float* w2W   = (const float*)d_in[12];
  const float* w2b   = (const float*)d_in[13];
  const float* projW = (const float*)d_in[14];
  const float* projb = (const float*)d_in[15];
  const float* ln2_g = (const float*)d_in[16];
  const float* ln2_b = (const float*)d_in[17];
  const float* fc1W  = (const float*)d_in[18];
  const float* fc1b  = (const float*)d_in[19];
  const float* fc2W  = (const float*)d_in[20];
  const float* fc2b  = (const float*)d_in[21];
  float* out = (float*)d_out;
  float* ws  = (float*)d_ws;

  const int ksplit = (ws_size >= (size_t)WS_KSEND * 4) ? 1 : 0;

  k_q    <<<dim3(12, 64), dim3(256), 0, stream>>>(x_cls, ln1_g, ln1_b, Wq, bq, ws);
  k_gqk  <<<dim3(6, 64),  dim3(256), 0, stream>>>(ln1_g, ln1_b, Wk, w1W, ws);
  k_main1<<<dim3(13, 64, ksplit ? 2 : 1), dim3(256), 0, stream>>>(x_cls, x_img, ws);
  k_sm_a <<<dim3(4, 64),  dim3(256), 0, stream>>>(bk, w1W, w1b, ws, ksplit);
  k_sm_b <<<dim3(4, 64),  dim3(256), 0, stream>>>(w2W, w2b, ws);
  k_wsum <<<dim3(12, 64), dim3(512), 0, stream>>>(x_cls, x_img, out, ws);
  k_att_o<<<dim3(32, 64), dim3(192), 0, stream>>>(ln1_g, ln1_b, Wv, bv, ws);
  k_proj2<<<dim3(12, 64), dim3(256), 0, stream>>>(x_cls, projW, projb, ws);
  k_fc1  <<<dim3(96),     dim3(256), 0, stream>>>(fc1W, fc1b, ln2_g, ln2_b, ws);
  k_fc2  <<<dim3(12, 4, 2), dim3(256), 0, stream>>>(fc2W, ws);
  k_final<<<dim3(192),    dim3(256), 0, stream>>>(fc2b, out, ws);
}